// Round 2
// baseline (488.783 us; speedup 1.0000x reference)
//
#include <hip/hip_runtime.h>

// Problem constants
#define N_ROWS 65536      // B*H*W = 16*64*64
#define NE 1024           // n_e
#define E_DIM 64
#define HALF 512          // codes per K1 block (codebook split in 2)
#define CHUNK 128         // codes per LDS chunk
#define NCHUNK 4          // HALF/CHUNK

// d_out float layout: [0]=loss, [1..4194304]=quantized(B,C,H,W), [4194305]=perplexity, [4194306..]=encodings(N,1024)
#define Q_OFF 1
#define P_OFF 4194305
#define ENC_OFF 4194306

typedef float f32x2 __attribute__((ext_vector_type(2)));

// ---------------- K0: embed norms (0.5*||e||^2), zero hist & loss accum ----------------
__global__ __launch_bounds__(256) void k0_prep(const float* __restrict__ emb,
                                               float* __restrict__ enorm,
                                               int* __restrict__ hist,
                                               float* __restrict__ lacc) {
    int j = blockIdx.x * 256 + threadIdx.x;   // 0..1023
    const float4* row = (const float4*)(emb + j * E_DIM);
    float s = 0.f;
#pragma unroll
    for (int k = 0; k < 16; ++k) {
        float4 v = row[k];
        s += v.x * v.x + v.y * v.y + v.z * v.z + v.w * v.w;
    }
    enorm[j] = 0.5f * s;
    hist[j] = 0;
    if (j == 0) *lacc = 0.f;
}

// ---------------- K1: per-row best (score,index) over one codebook half + encodings zero-fill ----------------
__global__ __launch_bounds__(256, 2) void k1_scores(
    const float* __restrict__ in, const float* __restrict__ emb,
    const float* __restrict__ enorm,
    float* __restrict__ cs, int* __restrict__ ci, float* __restrict__ xnw,
    float* __restrict__ out) {
    __shared__ float lds_e[CHUNK * E_DIM];   // 32 KB
    __shared__ float lds_n[CHUNK];
    const int tid = threadIdx.x;
    const int h = blockIdx.x & 1;
    const int rb = blockIdx.x >> 1;
    const int r = rb * 256 + tid;
    const int bbase = (r >> 12) * 262144 + (r & 4095);

    // load row into registers (coalesced per-c across lanes), compute ||x||^2
    float x[E_DIM];
    float xn = 0.f;
#pragma unroll
    for (int c = 0; c < E_DIM; ++c) {
        x[c] = in[bbase + c * 4096];
        xn += x[c] * x[c];
    }
    if (h == 0) xnw[r] = xn;

    float best = -1e30f;
    int bidx = 0;

    f32x2* enc2 = (f32x2*)(out + ENC_OFF);            // 8-byte aligned
    const size_t zb = (size_t)blockIdx.x * 65536;     // f2 elements per block

    for (int c0 = 0; c0 < NCHUNK; ++c0) {
        const int jbase = h * HALF + c0 * CHUNK;
        __syncthreads();
        const float4* src = (const float4*)(emb + (size_t)jbase * E_DIM);
        float4* dst = (float4*)lds_e;
#pragma unroll
        for (int k = 0; k < 8; ++k) dst[k * 256 + tid] = src[k * 256 + tid];
        if (tid < CHUNK) lds_n[tid] = enorm[jbase + tid];
        __syncthreads();

        for (int jj = 0; jj < CHUNK; ++jj) {
            // interleaved encodings zero-fill (fire-and-forget nt stores)
            if ((jj & 1) == 0) {
                int k = c0 * 64 + (jj >> 1);          // 0..255
                f32x2 z = {0.f, 0.f};
                __builtin_nontemporal_store(z, &enc2[zb + (size_t)k * 256 + tid]);
            }
            const float4* ev = (const float4*)(lds_e + jj * E_DIM);  // broadcast reads
            float a0 = 0.f, a1 = 0.f, a2 = 0.f, a3 = 0.f;
#pragma unroll
            for (int k = 0; k < 16; ++k) {
                float4 e = ev[k];
                a0 = fmaf(x[4 * k + 0], e.x, a0);
                a1 = fmaf(x[4 * k + 1], e.y, a1);
                a2 = fmaf(x[4 * k + 2], e.z, a2);
                a3 = fmaf(x[4 * k + 3], e.w, a3);
            }
            float s = (a0 + a1) + (a2 + a3) - lds_n[jj];
            if (s > best) { best = s; bidx = jbase + jj; }   // strict > => lowest index on tie
        }
    }
    cs[h * N_ROWS + r] = best;
    ci[h * N_ROWS + r] = bidx;
}

// ---------------- K2: combine halves, quantized gather, encoding ones, histogram, loss partials ----------------
__global__ __launch_bounds__(256) void k2_outputs(
    const float* __restrict__ emb,
    const float* __restrict__ cs, const int* __restrict__ ci,
    const float* __restrict__ xnw,
    int* __restrict__ hist, float* __restrict__ lacc,
    float* __restrict__ out) {
    __shared__ int lh[NE];
    __shared__ float lsum[4];
    const int tid = threadIdx.x;
#pragma unroll
    for (int k = 0; k < 4; ++k) lh[k * 256 + tid] = 0;
    __syncthreads();

    const int r = blockIdx.x * 256 + tid;
    float s0 = cs[r], s1 = cs[N_ROWS + r];
    int i0 = ci[r], i1 = ci[N_ROWS + r];
    int idx = (s1 > s0) ? i1 : i0;            // tie -> half0 (lower index), matches np.argmin
    float smax = (s1 > s0) ? s1 : s0;
    float dmin = xnw[r] - 2.f * smax;

    atomicAdd(&lh[idx], 1);

    // one-hot one
    out[ENC_OFF + (size_t)r * NE + idx] = 1.0f;

    // quantized: out[b][c][h][w] = emb[idx][c]
    const float4* erow = (const float4*)(emb + (size_t)idx * E_DIM);
    const int qb = Q_OFF + (r >> 12) * 262144 + (r & 4095);
#pragma unroll
    for (int k = 0; k < 16; ++k) {
        float4 e = erow[k];
        out[qb + (4 * k + 0) * 4096] = e.x;
        out[qb + (4 * k + 1) * 4096] = e.y;
        out[qb + (4 * k + 2) * 4096] = e.z;
        out[qb + (4 * k + 3) * 4096] = e.w;
    }

    // loss partial reduce (wave64 shuffle, then LDS across 4 waves)
    float v = dmin;
#pragma unroll
    for (int off = 32; off; off >>= 1) v += __shfl_down(v, off);
    if ((tid & 63) == 0) lsum[tid >> 6] = v;
    __syncthreads();
    if (tid == 0) atomicAdd(lacc, (lsum[0] + lsum[1]) + (lsum[2] + lsum[3]));

    // merge LDS histogram to global (barrier above also ordered lh atomics)
#pragma unroll
    for (int k = 0; k < 4; ++k) {
        int c = lh[k * 256 + tid];
        if (c) atomicAdd(&hist[k * 256 + tid], c);
    }
}

// ---------------- K3: scalars ----------------
__global__ __launch_bounds__(256) void k3_final(const int* __restrict__ hist,
                                                const float* __restrict__ lacc,
                                                float* __restrict__ out) {
    __shared__ float lsum[4];
    const int tid = threadIdx.x;
    float s = 0.f;
#pragma unroll
    for (int k = 0; k < 4; ++k) {
        float p = (float)hist[k * 256 + tid] * (1.0f / 65536.f);
        s += p * logf(p + 1e-10f);
    }
#pragma unroll
    for (int off = 32; off; off >>= 1) s += __shfl_down(s, off);
    if ((tid & 63) == 0) lsum[tid >> 6] = s;
    __syncthreads();
    if (tid == 0) {
        float ent = (lsum[0] + lsum[1]) + (lsum[2] + lsum[3]);
        out[P_OFF] = expf(-ent);                      // exp(-sum p*log(p+1e-10))
        out[0] = *lacc * (1.25f / 4194304.f);         // (1+beta)*mean since q_loss==e_loss in value
    }
}

extern "C" void kernel_launch(void* const* d_in, const int* in_sizes, int n_in,
                              void* d_out, int out_size, void* d_ws, size_t ws_size,
                              hipStream_t stream) {
    const float* in  = (const float*)d_in[0];
    const float* emb = (const float*)d_in[1];
    float* out = (float*)d_out;
    float* ws  = (float*)d_ws;

    float* cs    = ws;                              // [2][N] scores
    int*   ci    = (int*)(ws + 2 * N_ROWS);         // [2][N] indices
    float* xnw   = ws + 4 * N_ROWS;                 // [N] ||x||^2
    float* enorm = ws + 5 * N_ROWS;                 // [1024] 0.5*||e||^2
    int*   hist  = (int*)(ws + 5 * N_ROWS + 1024);  // [1024]
    float* lacc  = ws + 5 * N_ROWS + 2048;          // [1]

    k0_prep<<<4, 256, 0, stream>>>(emb, enorm, hist, lacc);
    k1_scores<<<512, 256, 0, stream>>>(in, emb, enorm, cs, ci, xnw, out);
    k2_outputs<<<256, 256, 0, stream>>>(emb, cs, ci, xnw, hist, lacc, out);
    k3_final<<<1, 256, 0, stream>>>(hist, lacc, out);
}

// Round 3
// 338.264 us; speedup vs baseline: 1.4450x; 1.4450x over previous
//
#include <hip/hip_runtime.h>

#define N_ROWS 65536
#define NE 1024
#define E_DIM 64
#define MB 128            // rows per block
#define CCH 128           // codes per LDS chunk
#define NCH 8             // chunks
#define LDS_PITCH 72      // shorts per LDS row (64 + 8 pad -> conflict-free)

// d_out float layout: [0]=loss, [1..4194304]=quantized, [4194305]=perplexity, [4194306..]=encodings
#define Q_OFF 1
#define P_OFF 4194305
#define ENC_OFF 4194306

typedef float f32x2 __attribute__((ext_vector_type(2)));
typedef float f32x4 __attribute__((ext_vector_type(4)));
typedef short bf16x8 __attribute__((ext_vector_type(8)));
typedef unsigned short u16x8 __attribute__((ext_vector_type(8)));

__device__ __forceinline__ short f2bf(float x) {
    union { float f; unsigned u; } v; v.f = x;
    unsigned r = v.u + 0x7FFF + ((v.u >> 16) & 1);   // RNE
    return (short)(r >> 16);
}
__device__ __forceinline__ float bf2f(short h) {
    union { float f; unsigned u; } v; v.u = ((unsigned)(unsigned short)h) << 16;
    return v.f;
}

// ---------------- K0: split-bf16 codebook + 0.5*||e||^2 + zero hist/lacc ----------------
__global__ __launch_bounds__(256) void k0_prep(const float* __restrict__ emb,
                                               ushort* __restrict__ ehi, ushort* __restrict__ elo,
                                               float* __restrict__ enorm,
                                               int* __restrict__ hist, float* __restrict__ lacc) {
    const int t = blockIdx.x * 256 + threadIdx.x;    // 0..4095
    const int code = t >> 2, part = t & 3;           // 4 threads per code, 16 elems each
    const float4* ep = (const float4*)(emb + code * 64 + part * 16);
    float s = 0.f;
    ushort h[16], l[16];
#pragma unroll
    for (int q = 0; q < 4; ++q) {
        float4 v = ep[q];
        float vv[4] = {v.x, v.y, v.z, v.w};
#pragma unroll
        for (int j = 0; j < 4; ++j) {
            float x = vv[j];
            s += x * x;
            short hh = f2bf(x);
            h[q * 4 + j] = (ushort)hh;
            l[q * 4 + j] = (ushort)f2bf(x - bf2f(hh));
        }
    }
    s += __shfl_xor(s, 1); s += __shfl_xor(s, 2);
    u16x8 ha, hb, la, lb;
#pragma unroll
    for (int j = 0; j < 8; ++j) { ha[j] = h[j]; hb[j] = h[8 + j]; la[j] = l[j]; lb[j] = l[8 + j]; }
    u16x8* hp = (u16x8*)(ehi + code * 64 + part * 16);
    u16x8* lp = (u16x8*)(elo + code * 64 + part * 16);
    hp[0] = ha; hp[1] = hb; lp[0] = la; lp[1] = lb;
    if (part == 0) enorm[code] = 0.5f * s;
    if (t < NE) hist[t] = 0;
    if (t == 0) *lacc = 0.f;
}

// ---------------- K1: fused MFMA scores + argmin + all big outputs ----------------
__global__ __launch_bounds__(256, 2) void k1_main(
    const float* __restrict__ in, const float* __restrict__ emb,
    const ushort* __restrict__ ehi, const ushort* __restrict__ elo,
    const float* __restrict__ enorm,
    int* __restrict__ hist, float* __restrict__ lacc,
    float* __restrict__ out) {
    __shared__ ushort lds_eh[CCH * LDS_PITCH];
    __shared__ ushort lds_el[CCH * LDS_PITCH];
    __shared__ float lds_en[CCH];
    __shared__ int   lds_idx[MB];
    __shared__ float lds_sc[MB];
    __shared__ float lds_xn[MB];
    __shared__ float lds_part[4];

    const int tid = threadIdx.x;
    const int wave = tid >> 6, lane = tid & 63;
    const int lr = lane & 15, kg = lane >> 4;
    const int r0b = blockIdx.x * MB;
    const int rw = r0b + wave * 32;

    // ---- A-fragment prep: lane holds row (lr), k = kg*8+j per half; split bf16 ----
    bf16x8 ah[2][2], al[2][2];
    float xn[2];
#pragma unroll
    for (int rt = 0; rt < 2; ++rt) {
        const int row = rw + rt * 16 + lr;
        const int base = ((row >> 12) * 262144) + (row & 4095);
        float acc2 = 0.f;
#pragma unroll
        for (int hh = 0; hh < 2; ++hh) {
            float xv[8];
#pragma unroll
            for (int j = 0; j < 8; ++j) xv[j] = in[base + (hh * 32 + kg * 8 + j) * 4096];
            bf16x8 hi8, lo8;
#pragma unroll
            for (int j = 0; j < 8; ++j) {
                acc2 += xv[j] * xv[j];
                short hv = f2bf(xv[j]);
                hi8[j] = hv;
                lo8[j] = f2bf(xv[j] - bf2f(hv));
            }
            ah[rt][hh] = hi8; al[rt][hh] = lo8;
        }
        acc2 += __shfl_xor(acc2, 16);
        acc2 += __shfl_xor(acc2, 32);
        xn[rt] = acc2;
    }

    float best[2][4]; int bidx[2][4];
#pragma unroll
    for (int rt = 0; rt < 2; ++rt)
#pragma unroll
        for (int i = 0; i < 4; ++i) { best[rt][i] = -1e30f; bidx[rt][i] = 0; }

    const uint4* ehp = (const uint4*)ehi;
    const uint4* elp = (const uint4*)elo;
    float* encbase = out + ENC_OFF;

    for (int c0 = 0; c0 < NCH; ++c0) {
        const int n0 = c0 * CCH;
        __syncthreads();
#pragma unroll
        for (int i = 0; i < 4; ++i) {
            int m = i * 256 + tid;            // 0..1023
            int row = m >> 3, cg = m & 7;
            uint4 vh = ehp[(n0 + row) * 8 + cg];
            uint4 vl = elp[(n0 + row) * 8 + cg];
            *(uint4*)&lds_eh[row * LDS_PITCH + cg * 8] = vh;
            *(uint4*)&lds_el[row * LDS_PITCH + cg * 8] = vl;
        }
        if (tid < CCH) lds_en[tid] = enorm[n0 + tid];
        __syncthreads();

        for (int t = 0; t < 8; ++t) {
            // interleaved encodings zero-fill: 4 x f32x2 nt stores per tile-iter
            {
                const int m0 = c0 * 32 + t * 4;            // 0..255
#pragma unroll
                for (int z = 0; z < 4; ++z) {
                    int mm = m0 + z;
                    int rr = mm >> 3, s = mm & 7;          // row-in-wave-group, slot
                    f32x2 zv = {0.f, 0.f};
                    __builtin_nontemporal_store(zv,
                        (f32x2*)(encbase + (size_t)(rw + rr) * 1024) + s * 64 + lane);
                }
            }
            const int bro = (t * 16 + lr) * LDS_PITCH + kg * 8;
            bf16x8 bh0 = *(const bf16x8*)&lds_eh[bro];
            bf16x8 bh1 = *(const bf16x8*)&lds_eh[bro + 32];
            bf16x8 bl0 = *(const bf16x8*)&lds_el[bro];
            bf16x8 bl1 = *(const bf16x8*)&lds_el[bro + 32];
            const float en = lds_en[t * 16 + lr];
            const int code = n0 + t * 16 + lr;
#pragma unroll
            for (int rt = 0; rt < 2; ++rt) {
                f32x4 acc = {0.f, 0.f, 0.f, 0.f};
                acc = __builtin_amdgcn_mfma_f32_16x16x32_bf16(al[rt][0], bh0, acc, 0, 0, 0);
                acc = __builtin_amdgcn_mfma_f32_16x16x32_bf16(al[rt][1], bh1, acc, 0, 0, 0);
                acc = __builtin_amdgcn_mfma_f32_16x16x32_bf16(ah[rt][0], bl0, acc, 0, 0, 0);
                acc = __builtin_amdgcn_mfma_f32_16x16x32_bf16(ah[rt][1], bl1, acc, 0, 0, 0);
                acc = __builtin_amdgcn_mfma_f32_16x16x32_bf16(ah[rt][0], bh0, acc, 0, 0, 0);
                acc = __builtin_amdgcn_mfma_f32_16x16x32_bf16(ah[rt][1], bh1, acc, 0, 0, 0);
#pragma unroll
                for (int i = 0; i < 4; ++i) {
                    float sc = acc[i] - en;
                    if (sc > best[rt][i]) { best[rt][i] = sc; bidx[rt][i] = code; }
                }
            }
        }
    }

    // ---- cross-lane argmin over the 16 codes held per lane-group ----
#pragma unroll
    for (int mask = 1; mask <= 8; mask <<= 1) {
#pragma unroll
        for (int rt = 0; rt < 2; ++rt)
#pragma unroll
            for (int i = 0; i < 4; ++i) {
                float os = __shfl_xor(best[rt][i], mask);
                int   oi = __shfl_xor(bidx[rt][i], mask);
                if (os > best[rt][i] || (os == best[rt][i] && oi < bidx[rt][i])) {
                    best[rt][i] = os; bidx[rt][i] = oi;
                }
            }
    }
    if (lr == 0) {
#pragma unroll
        for (int rt = 0; rt < 2; ++rt)
#pragma unroll
            for (int i = 0; i < 4; ++i) {
                int rl = wave * 32 + rt * 16 + kg * 4 + i;
                lds_idx[rl] = bidx[rt][i];
                lds_sc[rl] = best[rt][i];
            }
    }
    if (kg == 0) {
#pragma unroll
        for (int rt = 0; rt < 2; ++rt) lds_xn[wave * 32 + rt * 16 + lane] = xn[rt];
    }
    __syncthreads();

    // ---- loss + histogram ----
    float dm = 0.f;
    if (tid < MB) {
        int idx = lds_idx[tid];
        dm = lds_xn[tid] - 2.f * lds_sc[tid];
        atomicAdd(&hist[idx], 1);
    }
#pragma unroll
    for (int off = 32; off; off >>= 1) dm += __shfl_down(dm, off);
    if (lane == 0) lds_part[wave] = dm;
    __syncthreads();
    if (tid == 0) atomicAdd(lacc, (lds_part[0] + lds_part[1]) + (lds_part[2] + lds_part[3]));

    // ---- the '1' per encodings row (same lane & same 8B chunk as its zero store) ----
    for (int rr = 0; rr < 32; ++rr) {
        int rl = wave * 32 + rr;
        int idx = lds_idx[rl];
        if (lane == ((idx >> 1) & 63)) {
            f32x2 v = {0.f, 0.f};
            v[idx & 1] = 1.f;
            __builtin_nontemporal_store(v,
                (f32x2*)(encbase + (size_t)(r0b + rl) * 1024) + (idx >> 1));
        }
    }

    // ---- quantized gather (exact fp32 from emb) ----
    const float4* emb4 = (const float4*)emb;
#pragma unroll
    for (int i = 0; i < 8; ++i) {
        int lin = i * 256 + tid;              // 0..2047
        int rl = lin & 127, cq = lin >> 7;    // cq 0..15
        int idx = lds_idx[rl];
        float4 v = emb4[idx * 16 + cq];
        int row = r0b + rl;
        int qb = Q_OFF + ((row >> 12) * 262144) + (row & 4095);
        out[qb + (cq * 4 + 0) * 4096] = v.x;
        out[qb + (cq * 4 + 1) * 4096] = v.y;
        out[qb + (cq * 4 + 2) * 4096] = v.z;
        out[qb + (cq * 4 + 3) * 4096] = v.w;
    }
}

// ---------------- K3: scalars ----------------
__global__ __launch_bounds__(256) void k3_final(const int* __restrict__ hist,
                                                const float* __restrict__ lacc,
                                                float* __restrict__ out) {
    __shared__ float lsum[4];
    const int tid = threadIdx.x;
    float s = 0.f;
#pragma unroll
    for (int k = 0; k < 4; ++k) {
        float p = (float)hist[k * 256 + tid] * (1.0f / 65536.f);
        s += p * logf(p + 1e-10f);
    }
#pragma unroll
    for (int off = 32; off; off >>= 1) s += __shfl_down(s, off);
    if ((tid & 63) == 0) lsum[tid >> 6] = s;
    __syncthreads();
    if (tid == 0) {
        float ent = (lsum[0] + lsum[1]) + (lsum[2] + lsum[3]);
        out[P_OFF] = expf(-ent);
        out[0] = *lacc * (1.25f / 4194304.f);   // (1+beta)*mean; q_loss==e_loss in value
    }
}

extern "C" void kernel_launch(void* const* d_in, const int* in_sizes, int n_in,
                              void* d_out, int out_size, void* d_ws, size_t ws_size,
                              hipStream_t stream) {
    const float* in  = (const float*)d_in[0];
    const float* emb = (const float*)d_in[1];
    float* out = (float*)d_out;

    ushort* ehi  = (ushort*)d_ws;                   // 1024*64 shorts
    ushort* elo  = ehi + NE * E_DIM;                // 1024*64 shorts
    float* enorm = (float*)(elo + NE * E_DIM);      // 1024 f
    int*   hist  = (int*)(enorm + NE);              // 1024 i
    float* lacc  = (float*)(hist + NE);             // 1 f

    k0_prep<<<16, 256, 0, stream>>>(emb, ehi, elo, enorm, hist, lacc);
    k1_main<<<512, 256, 0, stream>>>(in, emb, ehi, elo, enorm, hist, lacc, out);
    k3_final<<<1, 256, 0, stream>>>(hist, lacc, out);
}